// Round 3
// baseline (385.987 us; speedup 1.0000x reference)
//
#include <hip/hip_runtime.h>
#include <hip/hip_bf16.h>
#include <stdint.h>

#define S_DIM 512
#define I_DIM 384
#define CMSA  64
#define CDIM  32
#define M_DIM (I_DIM*CDIM)   // 12288
#define P_DIM 128

typedef __attribute__((ext_vector_type(8))) short  s16x8;
typedef __attribute__((ext_vector_type(8))) __bf16 bf16x8;
typedef __attribute__((ext_vector_type(4))) float  f32x4;

static __device__ __forceinline__ unsigned short f2bf(float f) {
  union { float f; unsigned u; } v; v.f = f;
  unsigned r = v.u + 0x7FFFu + ((v.u >> 16) & 1u);
  return (unsigned short)(r >> 16);
}

static __device__ __forceinline__ void gload_lds16(const void* g, void* l) {
  __builtin_amdgcn_global_load_lds(
      (__attribute__((address_space(1))) void*)(g),
      (__attribute__((address_space(3))) void*)(l), 16, 0, 0);
}

#define VMCNT4() asm volatile("s_waitcnt vmcnt(4)" ::: "memory")
#define VMCNT0() asm volatile("s_waitcnt vmcnt(0)" ::: "memory")
#define BAR()    do { __builtin_amdgcn_s_barrier(); asm volatile("" ::: "memory"); } while (0)

// ---------------------------------------------------------------------------
// Kernel 1: LayerNorm + dual projection, wave-per-row.
// Lane layout: c = l&31 (output channel), h = l>>5 (k-half).
// w_a/w_b held in registers (32 floats each per lane); 1/512 folded into w_a.
// Per row: coalesced 256B msa load, 12-shfl LN reduce, LDS bounce for
// k-redistribution, 64 register FMAs, pair-sum shfl.
// Output staged in dword-swizzled LDS, written as 16B coalesced stores.
// Layout out: Ag/Bg[m = i*32+c][s], s contiguous.
// ---------------------------------------------------------------------------
__global__ __launch_bounds__(256) void ln_proj_kernel(
    const float* __restrict__ msa, const float* __restrict__ gamma,
    const float* __restrict__ beta, const float* __restrict__ w_a,
    const float* __restrict__ w_b, unsigned short* __restrict__ Ag,
    unsigned short* __restrict__ Bg)
{
  __shared__ float mraw[4][64];
  __shared__ unsigned int atr[64][32];   // [row=c*2+h][sp dword], swizzled sp^(row&31)

  const int tid = threadIdx.x;
  const int l = tid & 63, w = tid >> 6;
  const int c = l & 31, h = l >> 5;
  const int i = blockIdx.y;
  const int s0 = blockIdx.x * 64;

  // per-lane weight registers: wa[j] = w_a[c][h*32+j] * (1/512), wb[j] = w_b[c][h*32+j]
  float wa[32], wb[32];
  #pragma unroll
  for (int j = 0; j < 8; ++j) {
    float4 va = *(const float4*)(w_a + c*64 + h*32 + j*4);
    float4 vb = *(const float4*)(w_b + c*64 + h*32 + j*4);
    wa[j*4+0] = va.x*(1.f/512.f); wa[j*4+1] = va.y*(1.f/512.f);
    wa[j*4+2] = va.z*(1.f/512.f); wa[j*4+3] = va.w*(1.f/512.f);
    wb[j*4+0] = vb.x; wb[j*4+1] = vb.y; wb[j*4+2] = vb.z; wb[j*4+3] = vb.w;
  }
  const float gam = gamma[l], bet = beta[l];

  const int srow_base = s0 + w*16;
  for (int tp = 0; tp < 8; ++tp) {
    float resa[2], resb[2];
    #pragma unroll
    for (int t = 0; t < 2; ++t) {
      const int s = srow_base + tp*2 + t;
      const float x = msa[((size_t)s * I_DIM + i) * CMSA + l];
      float sum = x, sq = x*x;
      #pragma unroll
      for (int d = 1; d < 64; d <<= 1) {
        sum += __shfl_xor(sum, d);
        sq  += __shfl_xor(sq, d);
      }
      const float mu = sum * (1.f/64.f);
      const float rstd = rsqrtf(sq*(1.f/64.f) - mu*mu + 1e-5f);
      const float mn = (x - mu) * rstd * gam + bet;
      mraw[w][l] = mn;
      float ta = 0.f, tb = 0.f;
      #pragma unroll
      for (int j = 0; j < 8; ++j) {
        float4 mv = *(const float4*)&mraw[w][h*32 + j*4];
        ta += mv.x*wa[j*4+0] + mv.y*wa[j*4+1] + mv.z*wa[j*4+2] + mv.w*wa[j*4+3];
        tb += mv.x*wb[j*4+0] + mv.y*wb[j*4+1] + mv.z*wb[j*4+2] + mv.w*wb[j*4+3];
      }
      ta += __shfl_xor(ta, 32);
      tb += __shfl_xor(tb, 32);
      resa[t] = ta; resb[t] = tb;
    }
    // h==0 lanes write a, h==1 lanes write b (both halves hold both sums)
    const float v0 = h ? resb[0] : resa[0];
    const float v1 = h ? resb[1] : resa[1];
    const unsigned int pk = (unsigned int)f2bf(v0) | ((unsigned int)f2bf(v1) << 16);
    const int row = c*2 + h;
    const int sp = w*8 + tp;             // dword index: s_local = sp*2, sp*2+1
    atr[row][sp ^ (row & 31)] = pk;
  }
  __syncthreads();

  // writeout: thread t -> row = t>>2, 8 dwords starting at sp0=(t&3)*8
  const int row = tid >> 2, sp0 = (tid & 3) * 8;
  const int oc = row >> 1, ab = row & 1;
  unsigned int dw[8];
  #pragma unroll
  for (int j = 0; j < 8; ++j) dw[j] = atr[row][(sp0 + j) ^ (row & 31)];
  unsigned short* dst = (ab ? Bg : Ag) + ((size_t)i*CDIM + oc)*S_DIM + s0 + sp0*2;
  uint4 u0, u1;
  u0.x = dw[0]; u0.y = dw[1]; u0.z = dw[2]; u0.w = dw[3];
  u1.x = dw[4]; u1.y = dw[5]; u1.z = dw[6]; u1.w = dw[7];
  *(uint4*)(dst)     = u0;
  *(uint4*)(dst + 8) = u1;
}

// ---------------------------------------------------------------------------
// Kernel 2: w_out fp32 -> bf16 with k-permutation: Wp[p][d*32+c] = w[p][c*32+d]
// ---------------------------------------------------------------------------
__global__ __launch_bounds__(256) void wconv_kernel(
    const float* __restrict__ w, unsigned short* __restrict__ wp)
{
  const int idx = blockIdx.x * 256 + threadIdx.x;   // 131072 total
  const int p = idx >> 10, k = idx & 1023;
  const int cc = k >> 5, d = k & 31;
  wp[p*1024 + d*32 + cc] = f2bf(w[idx]);
}

// ---------------------------------------------------------------------------
// Kernel 3: fused GEMM, 256x256 tile, 8 waves (2M x 4N), BK=64, LDS dbuf,
// counted-vmcnt 2-sub-phase schedule (raw s_barrier, vmcnt(4) once per kt).
// ---------------------------------------------------------------------------
__global__ __launch_bounds__(512, 2) void opm_gemm_kernel(
    const unsigned short* __restrict__ Ag, const unsigned short* __restrict__ Bg,
    const unsigned short* __restrict__ Wp, const float* __restrict__ b_out,
    float* __restrict__ z)
{
  __shared__ __align__(16) unsigned char lds[131072];  // A dbuf 64K | B dbuf 64K; reused as O_lT

  const int tid = threadIdx.x;
  const int l = tid & 63, w = tid >> 6;
  const int wr = w >> 2, wc = w & 3;          // 2M x 4N wave grid

  // T1: bijective XCD swizzle, bm-inner
  const int bid = blockIdx.x;                 // 0..2303 (2304 % 8 == 0)
  const int xcd = bid & 7, local = bid >> 3;
  const int bn = local / 6;
  const int bm = xcd * 6 + (local % 6);

  // staging: 4x16B units per thread per matrix; its 0,1 = halves 0 (rows 0..127)
  const unsigned short* pA[4];
  const unsigned short* pB[4];
  int u16[4];
  #pragma unroll
  for (int it = 0; it < 4; ++it) {
    const int u = it*512 + tid;               // 0..2047
    const int r = u >> 3, slot = u & 7;
    const int ks8 = slot ^ (r & 7);           // inverse swizzle on global source
    pA[it] = Ag + ((size_t)(bm*256 + r))*S_DIM + ks8*8;
    pB[it] = Bg + ((size_t)(bn*256 + r))*S_DIM + ks8*8;
    u16[it] = u * 16;
  }

  int a_base[8], b_base[4];
  #pragma unroll
  for (int mi = 0; mi < 8; ++mi) {
    const int rowA = wr*128 + mi*16 + (l & 15);
    a_base[mi] = rowA*128 + ((((l >> 4)) ^ (rowA & 7)) << 4);
  }
  #pragma unroll
  for (int ni = 0; ni < 4; ++ni) {
    const int rowB = wc*64 + ni*16 + (l & 15);
    b_base[ni] = 65536 + rowB*128 + ((((l >> 4)) ^ (rowB & 7)) << 4);
  }

  f32x4 acc[8][4];
  #pragma unroll
  for (int a = 0; a < 8; ++a)
    #pragma unroll
    for (int b = 0; b < 4; ++b)
      acc[a][b] = (f32x4){0.f, 0.f, 0.f, 0.f};

  // prologue: stage kt=0 fully into buf 0 (group0: its 0,1; group1: its 2,3)
  #pragma unroll
  for (int it = 0; it < 4; ++it) {
    gload_lds16(pA[it], lds + u16[it]);
    gload_lds16(pB[it], lds + 65536 + u16[it]);
    pA[it] += 64; pB[it] += 64;
  }

  int cur = 0;
  for (int kt = 0; kt < 8; ++kt) {
    const int cb = cur * 32768;
    const int nb = (cur ^ 1) * 32768;
    // ---- phase 0 (ks=0): issue group0 of kt+1, wait kt's tile, compute ----
    if (kt < 7) {
      #pragma unroll
      for (int it = 0; it < 2; ++it) {
        gload_lds16(pA[it], lds + nb + u16[it]);
        gload_lds16(pB[it], lds + 65536 + nb + u16[it]);
      }
      VMCNT4();
    } else {
      VMCNT0();
    }
    BAR();
    #pragma unroll
    for (int ks = 0; ks < 2; ++ks) {
      bf16x8 af[8], bf[4];
      const int kx = ks << 6;
      #pragma unroll
      for (int mi = 0; mi < 8; ++mi)
        af[mi] = *(const bf16x8*)(lds + cb + (a_base[mi] ^ kx));
      #pragma unroll
      for (int ni = 0; ni < 4; ++ni)
        bf[ni] = *(const bf16x8*)(lds + cb + (b_base[ni] ^ kx));
      __builtin_amdgcn_s_setprio(1);
      #pragma unroll
      for (int mi = 0; mi < 8; ++mi)
        #pragma unroll
        for (int ni = 0; ni < 4; ++ni)
          acc[mi][ni] = __builtin_amdgcn_mfma_f32_16x16x32_bf16(
              af[mi], bf[ni], acc[mi][ni], 0, 0, 0);
      __builtin_amdgcn_s_setprio(0);
      // ---- phase 1 (ks=1): issue group1 of kt+1, barrier, compute ----
      if (ks == 0) {
        if (kt < 7) {
          #pragma unroll
          for (int it = 2; it < 4; ++it) {
            gload_lds16(pA[it], lds + nb + u16[it]);
            gload_lds16(pB[it], lds + 65536 + nb + u16[it]);
          }
        }
        BAR();
      }
    }
    if (kt < 7) {
      #pragma unroll
      for (int it = 0; it < 4; ++it) { pA[it] += 64; pB[it] += 64; }
    }
    BAR();   // end-of-kt: all reads of buf[cur] retired before kt+2 staging
    cur ^= 1;
  }

  // ---- epilogue A: acc -> O_lT[pair][k'=d*32+c], bf16, dual XOR swizzle ----
  #pragma unroll
  for (int mi = 0; mi < 8; ++mi) {
    const int iloc = wr*4 + (mi >> 1);
    const int cb2 = (mi & 1)*16 + (l >> 4)*4;
    #pragma unroll
    for (int ni = 0; ni < 4; ++ni) {
      const int jloc = wc*2 + (ni >> 1);
      const int d = (ni & 1)*16 + (l & 15);
      const int pair = iloc*8 + jloc;
      #pragma unroll
      for (int rp = 0; rp < 2; ++rp) {
        const int kp = d*32 + cb2 + 2*rp;              // even
        int byte = pair*2048 + kp*2;
        byte ^= ((pair & 7) << 4) ^ (((byte >> 7) & 7) << 4);
        unsigned int val = (unsigned int)f2bf(acc[mi][ni][2*rp])
                         | ((unsigned int)f2bf(acc[mi][ni][2*rp+1]) << 16);
        *(unsigned int*)(lds + byte) = val;
      }
    }
  }
  __syncthreads();

  // ---- epilogue B: z = Wp @ O_lT^T ; wave w owns p-rows [w*16, w*16+16) ----
  const unsigned short* wrow = Wp + ((size_t)(w*16 + (l & 15)))*1024 + (l >> 4)*8;
  f32x4 accz[4];
  #pragma unroll
  for (int ni = 0; ni < 4; ++ni) accz[ni] = (f32x4){0.f,0.f,0.f,0.f};

  #pragma unroll 4
  for (int ksp = 0; ksp < 32; ++ksp) {
    const bf16x8 wf = *(const bf16x8*)(wrow + ksp*32);
    const int kbyte = ksp*64 + (l >> 4)*16;
    const int kswz = ((kbyte >> 7) & 7) << 4;
    #pragma unroll
    for (int ni = 0; ni < 4; ++ni) {
      const int pair = ni*16 + (l & 15);
      int byte = pair*2048 + kbyte;
      byte ^= ((pair & 7) << 4) ^ kswz;
      const bf16x8 of = *(const bf16x8*)(lds + byte);
      accz[ni] = __builtin_amdgcn_mfma_f32_16x16x32_bf16(wf, of, accz[ni], 0, 0, 0);
    }
  }

  // ---- store z + b_out (float4 over consecutive p) ----
  const int p0 = w*16 + (l >> 4)*4;
  const float4 bo = *(const float4*)(b_out + p0);
  #pragma unroll
  for (int ni = 0; ni < 4; ++ni) {
    const int pair = ni*16 + (l & 15);
    const int gi = bm*8 + (pair >> 3), gj = bn*8 + (pair & 7);
    float4 v;
    v.x = accz[ni][0] + bo.x; v.y = accz[ni][1] + bo.y;
    v.z = accz[ni][2] + bo.z; v.w = accz[ni][3] + bo.w;
    *(float4*)(z + ((size_t)gi * I_DIM + gj) * P_DIM + p0) = v;
  }
}

extern "C" void kernel_launch(void* const* d_in, const int* in_sizes, int n_in,
                              void* d_out, int out_size, void* d_ws, size_t ws_size,
                              hipStream_t stream) {
  const float* msa   = (const float*)d_in[0];
  const float* gamma = (const float*)d_in[1];
  const float* beta  = (const float*)d_in[2];
  const float* w_a   = (const float*)d_in[3];
  const float* w_b   = (const float*)d_in[4];
  const float* w_out = (const float*)d_in[5];
  const float* b_out = (const float*)d_in[6];
  float* z = (float*)d_out;

  unsigned short* Ag = (unsigned short*)d_ws;                 // 12.6 MB
  unsigned short* Bg = Ag + (size_t)M_DIM * S_DIM;            // 12.6 MB
  unsigned short* Wp = Bg + (size_t)M_DIM * S_DIM;            // 256 KB

  hipLaunchKernelGGL(ln_proj_kernel, dim3(8, 384), dim3(256), 0, stream,
                     msa, gamma, beta, w_a, w_b, Ag, Bg);
  hipLaunchKernelGGL(wconv_kernel, dim3(512), dim3(256), 0, stream, w_out, Wp);
  hipLaunchKernelGGL(opm_gemm_kernel, dim3(2304), dim3(512), 0, stream,
                     Ag, Bg, Wp, b_out, z);
}

// Round 5
// 377.174 us; speedup vs baseline: 1.0234x; 1.0234x over previous
//
#include <hip/hip_runtime.h>
#include <hip/hip_bf16.h>
#include <stdint.h>

#define S_DIM 512
#define I_DIM 384
#define CMSA  64
#define CDIM  32
#define M_DIM (I_DIM*CDIM)   // 12288
#define P_DIM 128

typedef __attribute__((ext_vector_type(8))) short  s16x8;
typedef __attribute__((ext_vector_type(8))) __bf16 bf16x8;
typedef __attribute__((ext_vector_type(4))) float  f32x4;

static __device__ __forceinline__ unsigned short f2bf(float f) {
  union { float f; unsigned u; } v; v.f = f;
  unsigned r = v.u + 0x7FFFu + ((v.u >> 16) & 1u);
  return (unsigned short)(r >> 16);
}

static __device__ __forceinline__ void gload_lds16(const void* g, void* l) {
  __builtin_amdgcn_global_load_lds(
      (__attribute__((address_space(1))) void*)(g),
      (__attribute__((address_space(3))) void*)(l), 16, 0, 0);
}

#define VMCNT4() asm volatile("s_waitcnt vmcnt(4)" ::: "memory")
#define VMCNT0() asm volatile("s_waitcnt vmcnt(0)" ::: "memory")
#define BAR()    do { __builtin_amdgcn_s_barrier(); asm volatile("" ::: "memory"); } while (0)

// ---------------------------------------------------------------------------
// Kernel 1: LayerNorm + dual projection (R1/R2-proven arrangement).
// grid (8 s-blocks, 384 i); each 4-lane group owns one (s,i) row.
// 1/512 folded into A. Out: Ag/Bg[m = i*32+c][s], s contiguous.
// ---------------------------------------------------------------------------
__global__ __launch_bounds__(256) void ln_proj_kernel(
    const float* __restrict__ msa, const float* __restrict__ gamma,
    const float* __restrict__ beta, const float* __restrict__ w_a,
    const float* __restrict__ w_b, unsigned short* __restrict__ Ag,
    unsigned short* __restrict__ Bg)
{
  __shared__ float wl[2][32][64];
  __shared__ float gb[2][64];
  __shared__ unsigned short atr[2][32][64];

  const int tid = threadIdx.x;
  float* wflat = &wl[0][0][0];
  for (int t = tid; t < 2048; t += 256) { wflat[t] = w_a[t]; wflat[2048 + t] = w_b[t]; }
  if (tid < 64) { gb[0][tid] = gamma[tid]; gb[1][tid] = beta[tid]; }
  __syncthreads();

  const int q = tid & 3, sl = tid >> 2;
  const int s = blockIdx.x * 64 + sl;
  const int i = blockIdx.y;
  const float* row = msa + ((size_t)s * I_DIM + i) * CMSA + q * 16;

  float x[16];
  #pragma unroll
  for (int u = 0; u < 4; ++u) {
    float4 v = *(const float4*)(row + 4*u);
    x[4*u] = v.x; x[4*u+1] = v.y; x[4*u+2] = v.z; x[4*u+3] = v.w;
  }
  float sum = 0.f, sq = 0.f;
  #pragma unroll
  for (int j = 0; j < 16; ++j) { sum += x[j]; sq += x[j]*x[j]; }
  sum += __shfl_xor(sum, 1); sum += __shfl_xor(sum, 2);
  sq  += __shfl_xor(sq, 1);  sq  += __shfl_xor(sq, 2);
  const float mean = sum * (1.f/64.f);
  const float var  = sq  * (1.f/64.f) - mean*mean;
  const float rstd = rsqrtf(var + 1e-5f);
  float m[16];
  #pragma unroll
  for (int j = 0; j < 16; ++j)
    m[j] = (x[j] - mean) * rstd * gb[0][q*16+j] + gb[1][q*16+j];

  for (int c = 0; c < 32; ++c) {
    float pa = 0.f, pb = 0.f;
    #pragma unroll
    for (int u = 0; u < 4; ++u) {
      float4 wa = *(const float4*)&wl[0][c][q*16 + 4*u];
      float4 wb = *(const float4*)&wl[1][c][q*16 + 4*u];
      pa += m[4*u]*wa.x + m[4*u+1]*wa.y + m[4*u+2]*wa.z + m[4*u+3]*wa.w;
      pb += m[4*u]*wb.x + m[4*u+1]*wb.y + m[4*u+2]*wb.z + m[4*u+3]*wb.w;
    }
    pa += __shfl_xor(pa, 1); pa += __shfl_xor(pa, 2);
    pb += __shfl_xor(pb, 1); pb += __shfl_xor(pb, 2);
    if (q == 0) {
      atr[0][c][sl] = f2bf(pa * (1.f/512.f));
      atr[1][c][sl] = f2bf(pb);
    }
  }
  __syncthreads();
  const int c2 = tid >> 3, su = (tid & 7) * 8;
  const size_t gbase = ((size_t)i * CDIM + c2) * S_DIM + (size_t)blockIdx.x * 64 + su;
  *(s16x8*)(Ag + gbase) = *(const s16x8*)&atr[0][c2][su];
  *(s16x8*)(Bg + gbase) = *(const s16x8*)&atr[1][c2][su];
}

// ---------------------------------------------------------------------------
// Kernel 2: w_out fp32 -> bf16, k-permuted: Wp[p][d*32+c] = w[p][c*32+d]
// ---------------------------------------------------------------------------
__global__ __launch_bounds__(256) void wconv_kernel(
    const float* __restrict__ w, unsigned short* __restrict__ wp)
{
  const int idx = blockIdx.x * 256 + threadIdx.x;   // 131072 total
  const int p = idx >> 10, k = idx & 1023;
  const int cc = k >> 5, d = k & 31;
  wp[p*1024 + d*32 + cc] = f2bf(w[idx]);
}

// ---------------------------------------------------------------------------
// Kernel 3: fused GEMM, 256x256 tile, 8 waves (2M x 4N), BK=32,
// TRIPLE-buffered LDS (stage 2 K-tiles ahead), one barrier + one counted
// vmcnt(4) per K-tile. Epilogue = R2/R3-proven byte-addressed layout.
// ---------------------------------------------------------------------------
__global__ __launch_bounds__(512, 2) void opm_gemm_kernel(
    const unsigned short* __restrict__ Ag, const unsigned short* __restrict__ Bg,
    const unsigned short* __restrict__ Wp, const float* __restrict__ b_out,
    float* __restrict__ z)
{
  // main loop: 3 bufs x (A 16KB + B 16KB) = 96KB; epilogue O_lT: 64x2048 = 128KB
  __shared__ __align__(16) unsigned char lds[131072];

  const int tid = threadIdx.x;
  const int l = tid & 63, w = tid >> 6;
  const int wr = w >> 2, wc = w & 3;          // 2M x 4N wave grid

  // T1: bijective XCD swizzle, bm-inner
  const int bid = blockIdx.x;                 // 0..2303 (2304 % 8 == 0)
  const int xcd = bid & 7, local = bid >> 3;
  const int bn = local / 6;
  const int bm = xcd * 6 + (local % 6);

  // staging: linear copy. unit u = tid: row = tid>>2 (0..127), slot = tid&3.
  const unsigned short* a_src = Ag + ((size_t)(bm*256 + (tid >> 2)))*S_DIM + (tid & 3)*8;
  const unsigned short* b_src = Bg + ((size_t)(bn*256 + (tid >> 2)))*S_DIM + (tid & 3)*8;
  const int dst0 = tid * 16;

  // frag read offsets (buffer-relative; conflict-free at 64B row stride)
  int a_off[8], b_off[4];
  #pragma unroll
  for (int mi = 0; mi < 8; ++mi) {
    const int rowA = wr*128 + mi*16 + (l & 15);
    a_off[mi] = rowA*64 + ((l >> 4) * 16);
  }
  #pragma unroll
  for (int ni = 0; ni < 4; ++ni) {
    const int rowB = wc*64 + ni*16 + (l & 15);
    b_off[ni] = 16384 + rowB*64 + ((l >> 4) * 16);
  }

  f32x4 acc[8][4];
  #pragma unroll
  for (int a = 0; a < 8; ++a)
    #pragma unroll
    for (int b = 0; b < 4; ++b)
      acc[a][b] = (f32x4){0.f, 0.f, 0.f, 0.f};

  #define STAGE(kt, bb) do {                                                  \
    const unsigned short* as_ = a_src + (kt)*32;                              \
    const unsigned short* bs_ = b_src + (kt)*32;                              \
    unsigned char* lb_ = lds + (bb)*32768;                                    \
    gload_lds16(as_,             lb_ + dst0);                                 \
    gload_lds16(as_ + 128*S_DIM, lb_ + dst0 + 8192);                          \
    gload_lds16(bs_,             lb_ + 16384 + dst0);                         \
    gload_lds16(bs_ + 128*S_DIM, lb_ + 16384 + dst0 + 8192);                  \
  } while (0)

  // prologue: stage KT0->buf0, KT1->buf1; wait KT0; barrier
  STAGE(0, 0);
  STAGE(1, 1);
  VMCNT4();
  BAR();

  int cb = 0, sb = 2;   // compute buf = t%3, stage buf = (t+2)%3
  for (int t = 0; t < 16; ++t) {
    if (t < 14) STAGE(t + 2, sb);
    const int base = cb * 32768;
    bf16x8 af[8], bf[4];
    #pragma unroll
    for (int mi = 0; mi < 8; ++mi)
      af[mi] = *(const bf16x8*)(lds + base + a_off[mi]);
    #pragma unroll
    for (int ni = 0; ni < 4; ++ni)
      bf[ni] = *(const bf16x8*)(lds + base + b_off[ni]);
    __builtin_amdgcn_s_setprio(1);
    #pragma unroll
    for (int mi = 0; mi < 8; ++mi)
      #pragma unroll
      for (int ni = 0; ni < 4; ++ni)
        acc[mi][ni] = __builtin_amdgcn_mfma_f32_16x16x32_bf16(
            af[mi], bf[ni], acc[mi][ni], 0, 0, 0);
    __builtin_amdgcn_s_setprio(0);
    if (t < 14)       VMCNT4();   // KT(t+1) landed; KT(t+2) stays in flight
    else if (t == 14) VMCNT0();   // tail: KT15 landed
    BAR();
    cb = (cb == 2) ? 0 : cb + 1;
    sb = (sb == 2) ? 0 : sb + 1;
  }

  // ---- epilogue A (R2/R3-proven): acc -> O_lT[pair][k'=d*32+c], dual XOR ----
  #pragma unroll
  for (int mi = 0; mi < 8; ++mi) {
    const int iloc = wr*4 + (mi >> 1);
    const int cb2 = (mi & 1)*16 + (l >> 4)*4;
    #pragma unroll
    for (int ni = 0; ni < 4; ++ni) {
      const int jloc = wc*2 + (ni >> 1);
      const int d = (ni & 1)*16 + (l & 15);
      const int pair = iloc*8 + jloc;
      #pragma unroll
      for (int rp = 0; rp < 2; ++rp) {
        const int kp = d*32 + cb2 + 2*rp;              // even
        int byte = pair*2048 + kp*2;
        byte ^= ((pair & 7) << 4) ^ (((byte >> 7) & 7) << 4);
        unsigned int val = (unsigned int)f2bf(acc[mi][ni][2*rp])
                         | ((unsigned int)f2bf(acc[mi][ni][2*rp+1]) << 16);
        *(unsigned int*)(lds + byte) = val;
      }
    }
  }
  __syncthreads();

  // ---- epilogue B: z[128p][64pairs] = Wp(128x1024) @ O_lT^T ----
  const unsigned short* wrow = Wp + ((size_t)(w*16 + (l & 15)))*1024 + (l >> 4)*8;
  f32x4 accz[4];
  #pragma unroll
  for (int ni = 0; ni < 4; ++ni) accz[ni] = (f32x4){0.f,0.f,0.f,0.f};

  #pragma unroll 4
  for (int ksp = 0; ksp < 32; ++ksp) {
    const bf16x8 wf = *(const bf16x8*)(wrow + ksp*32);
    const int kbyte = ksp*64 + (l >> 4)*16;
    const int kswz = ((kbyte >> 7) & 7) << 4;
    #pragma unroll
    for (int ni = 0; ni < 4; ++ni) {
      const int pair = ni*16 + (l & 15);
      int byte = pair*2048 + kbyte;
      byte ^= ((pair & 7) << 4) ^ kswz;
      const bf16x8 of = *(const bf16x8*)(lds + byte);
      accz[ni] = __builtin_amdgcn_mfma_f32_16x16x32_bf16(wf, of, accz[ni], 0, 0, 0);
    }
  }

  // ---- store z + b_out (float4 over consecutive p) ----
  const int p0 = w*16 + (l >> 4)*4;
  const float4 bo = *(const float4*)(b_out + p0);
  #pragma unroll
  for (int ni = 0; ni < 4; ++ni) {
    const int pair = ni*16 + (l & 15);
    const int gi = bm*8 + (pair >> 3), gj = bn*8 + (pair & 7);
    float4 v;
    v.x = accz[ni][0] + bo.x; v.y = accz[ni][1] + bo.y;
    v.z = accz[ni][2] + bo.z; v.w = accz[ni][3] + bo.w;
    *(float4*)(z + ((size_t)gi * I_DIM + gj) * P_DIM + p0) = v;
  }
}

extern "C" void kernel_launch(void* const* d_in, const int* in_sizes, int n_in,
                              void* d_out, int out_size, void* d_ws, size_t ws_size,
                              hipStream_t stream) {
  const float* msa   = (const float*)d_in[0];
  const float* gamma = (const float*)d_in[1];
  const float* beta  = (const float*)d_in[2];
  const float* w_a   = (const float*)d_in[3];
  const float* w_b   = (const float*)d_in[4];
  const float* w_out = (const float*)d_in[5];
  const float* b_out = (const float*)d_in[6];
  float* z = (float*)d_out;

  unsigned short* Ag = (unsigned short*)d_ws;                 // 12.6 MB
  unsigned short* Bg = Ag + (size_t)M_DIM * S_DIM;            // 12.6 MB
  unsigned short* Wp = Bg + (size_t)M_DIM * S_DIM;            // 256 KB

  hipLaunchKernelGGL(ln_proj_kernel, dim3(8, 384), dim3(256), 0, stream,
                     msa, gamma, beta, w_a, w_b, Ag, Bg);
  hipLaunchKernelGGL(wconv_kernel, dim3(512), dim3(256), 0, stream, w_out, Wp);
  hipLaunchKernelGGL(opm_gemm_kernel, dim3(2304), dim3(512), 0, stream,
                     Ag, Bg, Wp, b_out, z);
}